// Round 8
// baseline (69.251 us; speedup 1.0000x reference)
//
#include <hip/hip_runtime.h>

// 3x3 valid cross-correlation + bias, fp32.
// x: 6144x6144, k: 3x3, bias scalar -> out: 6142x6142.
// R7: persistent band-walk with 8-row register ring buffer.
// Each thread: 4 cols x 48 rows. At step m: issue load of row m+7
// (slot (m+7)%8), compute row m from slots m,m+1,m+2 (all indices
// static via 8-step unrolled octets). Loop-carried prefetch => ~8
// wave-loads permanently in flight per wave; compiler cannot sink.
// Row read amplification 50/48 = 1.04x. Grid 768 blocks = 3/CU exact.
// XCD swizzle: 96 consecutive bands of one column strip per XCD.

#define W_IN  6144
#define H_IN  6144
#define OW    6142
#define OH    6142
#define BAND  48
#define NBANDS 128                  // 128*48 = 6144 >= 6142
#define GRID_X 6                    // 6*256 threads * 4 cols = 6144 >= 6142
#define NWG   (GRID_X * NBANDS)     // 768 = 8 XCDs * 96
#define WG_PER_XCD (NWG / 8)        // 96

typedef float f32x2 __attribute__((ext_vector_type(2)));
typedef float f32x4 __attribute__((ext_vector_type(4)));

// ---- main-path (4 output cols, needs 6 input cols) ----------------------

#define LOAD6(slot, rr)                                                      \
  {                                                                          \
    const int rr_ = (rr);                                                    \
    if (INTERIOR || rr_ < H_IN) {                                            \
      const float* p_ = x + rr_ * W_IN + c0;                                 \
      const f32x4 a_ = *reinterpret_cast<const f32x4*>(p_);                  \
      const f32x2 c_ = *reinterpret_cast<const f32x2*>(p_ + 4);              \
      v[slot][0] = a_.x; v[slot][1] = a_.y; v[slot][2] = a_.z;               \
      v[slot][3] = a_.w; v[slot][4] = c_.x; v[slot][5] = c_.y;               \
    } else {                                                                 \
      v[slot][0] = 0.f; v[slot][1] = 0.f; v[slot][2] = 0.f;                  \
      v[slot][3] = 0.f; v[slot][4] = 0.f; v[slot][5] = 0.f;                  \
    }                                                                        \
  }

#define STEP6(s, DO_LOAD)                                                    \
  {                                                                          \
    if (DO_LOAD) LOAD6(((s) + 7) & 7, rbase + (s) + 7);                      \
    const int rr = rbase + (s);                                              \
    if (INTERIOR || rr < OH) {                                               \
      const float (&ra)[6] = v[(s) & 7];                                     \
      const float (&rb)[6] = v[((s) + 1) & 7];                               \
      const float (&rc)[6] = v[((s) + 2) & 7];                               \
      float acc0 = bv + ra[0]*k00 + ra[1]*k01 + ra[2]*k02                    \
                      + rb[0]*k10 + rb[1]*k11 + rb[2]*k12                    \
                      + rc[0]*k20 + rc[1]*k21 + rc[2]*k22;                   \
      float acc1 = bv + ra[1]*k00 + ra[2]*k01 + ra[3]*k02                    \
                      + rb[1]*k10 + rb[2]*k11 + rb[3]*k12                    \
                      + rc[1]*k20 + rc[2]*k21 + rc[3]*k22;                   \
      float acc2 = bv + ra[2]*k00 + ra[3]*k01 + ra[4]*k02                    \
                      + rb[2]*k10 + rb[3]*k11 + rb[4]*k12                    \
                      + rc[2]*k20 + rc[3]*k21 + rc[4]*k22;                   \
      float acc3 = bv + ra[3]*k00 + ra[4]*k01 + ra[5]*k02                    \
                      + rb[3]*k10 + rb[4]*k11 + rb[5]*k12                    \
                      + rc[3]*k20 + rc[4]*k21 + rc[5]*k22;                   \
      float* po = out + rr * OW + c0;                                        \
      f32x2 s0_; s0_.x = acc0; s0_.y = acc1;                                 \
      f32x2 s1_; s1_.x = acc2; s1_.y = acc3;                                 \
      __builtin_nontemporal_store(s0_, reinterpret_cast<f32x2*>(po));        \
      __builtin_nontemporal_store(s1_, reinterpret_cast<f32x2*>(po + 2));    \
    }                                                                        \
  }

template <bool INTERIOR>
__device__ __forceinline__ void body_main(const float* __restrict__ x,
                                          float* __restrict__ out,
                                          int c0, int r0,
                                          float k00, float k01, float k02,
                                          float k10, float k11, float k12,
                                          float k20, float k21, float k22,
                                          float bv)
{
    float v[8][6];
    // Prologue: rows r0..r0+6 into slots 0..6.
#pragma unroll
    for (int r = 0; r < 7; ++r) LOAD6(r, r0 + r);

    int rbase = r0;
    for (int o = 0; o < 5; ++o) {   // rows 0..39: every step loads
        STEP6(0, true) STEP6(1, true) STEP6(2, true) STEP6(3, true)
        STEP6(4, true) STEP6(5, true) STEP6(6, true) STEP6(7, true)
        rbase += 8;
    }
    // Final octet: rows 40..47; only s<=2 load (rows r0+47..r0+49).
    STEP6(0, true) STEP6(1, true) STEP6(2, true) STEP6(3, false)
    STEP6(4, false) STEP6(5, false) STEP6(6, false) STEP6(7, false)
}

// ---- tail-path (c0 == 6140: 2 output cols, one float4 load) -------------

#define LOAD4(slot, rr)                                                      \
  {                                                                          \
    const int rr_ = (rr);                                                    \
    if (INTERIOR || rr_ < H_IN) {                                            \
      const f32x4 a_ = *reinterpret_cast<const f32x4*>(x + rr_ * W_IN + c0); \
      v[slot][0] = a_.x; v[slot][1] = a_.y; v[slot][2] = a_.z;               \
      v[slot][3] = a_.w;                                                     \
    } else {                                                                 \
      v[slot][0] = 0.f; v[slot][1] = 0.f; v[slot][2] = 0.f; v[slot][3] = 0.f;\
    }                                                                        \
  }

#define STEP4(s, DO_LOAD)                                                    \
  {                                                                          \
    if (DO_LOAD) LOAD4(((s) + 7) & 7, rbase + (s) + 7);                      \
    const int rr = rbase + (s);                                              \
    if (INTERIOR || rr < OH) {                                               \
      const float (&ra)[4] = v[(s) & 7];                                     \
      const float (&rb)[4] = v[((s) + 1) & 7];                               \
      const float (&rc)[4] = v[((s) + 2) & 7];                               \
      float a0 = bv + ra[0]*k00 + ra[1]*k01 + ra[2]*k02                      \
                    + rb[0]*k10 + rb[1]*k11 + rb[2]*k12                      \
                    + rc[0]*k20 + rc[1]*k21 + rc[2]*k22;                     \
      float a1 = bv + ra[1]*k00 + ra[2]*k01 + ra[3]*k02                      \
                    + rb[1]*k10 + rb[2]*k11 + rb[3]*k12                      \
                    + rc[1]*k20 + rc[2]*k21 + rc[3]*k22;                     \
      f32x2 s0_; s0_.x = a0; s0_.y = a1;                                     \
      __builtin_nontemporal_store(s0_,                                       \
          reinterpret_cast<f32x2*>(out + rr * OW + c0));                     \
    }                                                                        \
  }

template <bool INTERIOR>
__device__ __forceinline__ void body_tail(const float* __restrict__ x,
                                          float* __restrict__ out,
                                          int c0, int r0,
                                          float k00, float k01, float k02,
                                          float k10, float k11, float k12,
                                          float k20, float k21, float k22,
                                          float bv)
{
    float v[8][4];
#pragma unroll
    for (int r = 0; r < 7; ++r) LOAD4(r, r0 + r);

    int rbase = r0;
    for (int o = 0; o < 5; ++o) {
        STEP4(0, true) STEP4(1, true) STEP4(2, true) STEP4(3, true)
        STEP4(4, true) STEP4(5, true) STEP4(6, true) STEP4(7, true)
        rbase += 8;
    }
    STEP4(0, true) STEP4(1, true) STEP4(2, true) STEP4(3, false)
    STEP4(4, false) STEP4(5, false) STEP4(6, false) STEP4(7, false)
}

__global__ __launch_bounds__(256)
void corr2d_kernel(const float* __restrict__ x,
                   const float* __restrict__ kk,
                   const float* __restrict__ bias,
                   float* __restrict__ out) {
    // Chunked bijective XCD swizzle (768 % 8 == 0): XCD i gets bands
    // 96*i..96*i+95 in order -> y-adjacent bands share halo rows in L2.
    const int id = blockIdx.x;                        // 0..767
    const int wg = (id & 7) * WG_PER_XCD + (id >> 3); // bijection
    const int bx = wg / NBANDS;                       // 0..5   column strip
    const int by = wg - bx * NBANDS;                  // 0..127 row band

    const int t  = bx * 256 + (int)threadIdx.x;       // 0..1535
    const int c0 = t << 2;                            // 0,4,...,6140
    const int r0 = by * BAND;

    const float k00 = kk[0], k01 = kk[1], k02 = kk[2];
    const float k10 = kk[3], k11 = kk[4], k12 = kk[5];
    const float k20 = kk[6], k21 = kk[7], k22 = kk[8];
    const float bv = bias[0];

    // Interior iff every row index touched (loads reach r0+BAND+1) is valid
    // AND every output row < OH. Only the last band (by==127) is not.
    const bool interior = (r0 + BAND + 1) < H_IN;

    if (c0 + 4 <= OW) {
        if (interior) body_main<true >(x, out, c0, r0, k00, k01, k02, k10, k11, k12, k20, k21, k22, bv);
        else          body_main<false>(x, out, c0, r0, k00, k01, k02, k10, k11, k12, k20, k21, k22, bv);
    } else {
        if (interior) body_tail<true >(x, out, c0, r0, k00, k01, k02, k10, k11, k12, k20, k21, k22, bv);
        else          body_tail<false>(x, out, c0, r0, k00, k01, k02, k10, k11, k12, k20, k21, k22, bv);
    }
}

extern "C" void kernel_launch(void* const* d_in, const int* in_sizes, int n_in,
                              void* d_out, int out_size, void* d_ws, size_t ws_size,
                              hipStream_t stream) {
    const float* x    = (const float*)d_in[0];
    const float* k    = (const float*)d_in[1];
    const float* bias = (const float*)d_in[2];
    float* out        = (float*)d_out;

    dim3 block(256, 1, 1);
    dim3 grid(NWG, 1, 1);   // 768 blocks = 3 per CU exactly
    corr2d_kernel<<<grid, block, 0, stream>>>(x, k, bias, out);
}

// Round 9
// 51.716 us; speedup vs baseline: 1.3390x; 1.3390x over previous
//
#include <hip/hip_runtime.h>

// 3x3 valid cross-correlation + bias, fp32.
// x: 6144x6144, k: 3x3, bias scalar -> out: 6142x6142.
// R8: R5 structure (flat upfront row loads, compiler-rolled; XCD swizzle;
// float4+float2 loads, NT float2 stores) with ROWS 8 -> 12:
// vertical read amplification 1.25x -> 1.167x, logical traffic 341->328 MB,
// at the measured ~6.7 TB/s fabric ceiling -> ~48-50us.
// Grid 3072 blocks (= 8 XCDs * 384, 12 blocks/CU: TLP preserved).

#define W_IN  6144
#define H_IN  6144
#define OW    6142
#define OH    6142
#define ROWS  12
#define GRID_X 6                    // 6*256 threads * 4 cols = 6144 >= 6142
#define GRID_Y 512                  // ceil(6142/12)
#define NWG   (GRID_X * GRID_Y)     // 3072 = 8 XCDs * 384
#define WG_PER_XCD (NWG / 8)        // 384

typedef float f32x2 __attribute__((ext_vector_type(2)));
typedef float f32x4 __attribute__((ext_vector_type(4)));

template <bool INTERIOR>
__device__ __forceinline__ void body_main(const float* __restrict__ x,
                                          float* __restrict__ out,
                                          int c0, int r0,
                                          float k00, float k01, float k02,
                                          float k10, float k11, float k12,
                                          float k20, float k21, float k22,
                                          float bv)
{
    float v[ROWS + 2][6];
#pragma unroll
    for (int r = 0; r < ROWS + 2; ++r) {
        const int rr = r0 + r;
        if (INTERIOR || rr < H_IN) {
            const float* p = x + rr * W_IN + c0;
            const f32x4 a = *reinterpret_cast<const f32x4*>(p);
            const f32x2 c = *reinterpret_cast<const f32x2*>(p + 4);
            v[r][0] = a.x; v[r][1] = a.y; v[r][2] = a.z; v[r][3] = a.w;
            v[r][4] = c.x; v[r][5] = c.y;
        } else {
#pragma unroll
            for (int j = 0; j < 6; ++j) v[r][j] = 0.f;
        }
    }

#pragma unroll
    for (int m = 0; m < ROWS; ++m) {
        const int rr = r0 + m;
        if (INTERIOR || rr < OH) {
            float acc[4];
#pragma unroll
            for (int j = 0; j < 4; ++j) {
                acc[j] = bv
                    + v[m + 0][j] * k00 + v[m + 0][j + 1] * k01 + v[m + 0][j + 2] * k02
                    + v[m + 1][j] * k10 + v[m + 1][j + 1] * k11 + v[m + 1][j + 2] * k12
                    + v[m + 2][j] * k20 + v[m + 2][j + 1] * k21 + v[m + 2][j + 2] * k22;
            }
            float* po = out + rr * OW + c0;
            f32x2 s0; s0.x = acc[0]; s0.y = acc[1];
            f32x2 s1; s1.x = acc[2]; s1.y = acc[3];
            __builtin_nontemporal_store(s0, reinterpret_cast<f32x2*>(po));
            __builtin_nontemporal_store(s1, reinterpret_cast<f32x2*>(po + 2));
        }
    }
}

template <bool INTERIOR>
__device__ __forceinline__ void body_tail(const float* __restrict__ x,
                                          float* __restrict__ out,
                                          int c0, int r0,
                                          float k00, float k01, float k02,
                                          float k10, float k11, float k12,
                                          float k20, float k21, float k22,
                                          float bv)
{
    // c0 == 6140: output cols 6140..6141, input cols 6140..6143 (one float4).
    float v[ROWS + 2][4];
#pragma unroll
    for (int r = 0; r < ROWS + 2; ++r) {
        const int rr = r0 + r;
        if (INTERIOR || rr < H_IN) {
            const f32x4 a = *reinterpret_cast<const f32x4*>(x + rr * W_IN + c0);
            v[r][0] = a.x; v[r][1] = a.y; v[r][2] = a.z; v[r][3] = a.w;
        } else {
#pragma unroll
            for (int j = 0; j < 4; ++j) v[r][j] = 0.f;
        }
    }

#pragma unroll
    for (int m = 0; m < ROWS; ++m) {
        const int rr = r0 + m;
        if (INTERIOR || rr < OH) {
            float a0 = bv
                + v[m + 0][0] * k00 + v[m + 0][1] * k01 + v[m + 0][2] * k02
                + v[m + 1][0] * k10 + v[m + 1][1] * k11 + v[m + 1][2] * k12
                + v[m + 2][0] * k20 + v[m + 2][1] * k21 + v[m + 2][2] * k22;
            float a1 = bv
                + v[m + 0][1] * k00 + v[m + 0][2] * k01 + v[m + 0][3] * k02
                + v[m + 1][1] * k10 + v[m + 1][2] * k11 + v[m + 1][3] * k12
                + v[m + 2][1] * k20 + v[m + 2][2] * k21 + v[m + 2][3] * k22;
            f32x2 s0; s0.x = a0; s0.y = a1;
            __builtin_nontemporal_store(s0, reinterpret_cast<f32x2*>(out + rr * OW + c0));
        }
    }
}

__global__ __launch_bounds__(256)
void corr2d_kernel(const float* __restrict__ x,
                   const float* __restrict__ kk,
                   const float* __restrict__ bias,
                   float* __restrict__ out) {
    // Chunked bijective XCD swizzle: consecutive wg on one XCD are
    // y-adjacent bands of the same column strip -> halo rows L2-hit.
    const int id = blockIdx.x;                        // 0..3071
    const int wg = (id & 7) * WG_PER_XCD + (id >> 3); // bijection (3072 % 8 == 0)
    const int bx = wg / GRID_Y;                       // 0..5   column strip
    const int by = wg - bx * GRID_Y;                  // 0..511 row band

    const int t  = bx * 256 + (int)threadIdx.x;       // 0..1535
    const int c0 = t << 2;                            // 0,4,...,6140
    const int r0 = by * ROWS;

    const float k00 = kk[0], k01 = kk[1], k02 = kk[2];
    const float k10 = kk[3], k11 = kk[4], k12 = kk[5];
    const float k20 = kk[6], k21 = kk[7], k22 = kk[8];
    const float bv = bias[0];

    const bool interior = (r0 + ROWS + 1) < H_IN;     // input rows r0..r0+ROWS+1 all valid

    if (c0 + 4 <= OW) {
        if (interior) body_main<true >(x, out, c0, r0, k00, k01, k02, k10, k11, k12, k20, k21, k22, bv);
        else          body_main<false>(x, out, c0, r0, k00, k01, k02, k10, k11, k12, k20, k21, k22, bv);
    } else {
        if (interior) body_tail<true >(x, out, c0, r0, k00, k01, k02, k10, k11, k12, k20, k21, k22, bv);
        else          body_tail<false>(x, out, c0, r0, k00, k01, k02, k10, k11, k12, k20, k21, k22, bv);
    }
}

extern "C" void kernel_launch(void* const* d_in, const int* in_sizes, int n_in,
                              void* d_out, int out_size, void* d_ws, size_t ws_size,
                              hipStream_t stream) {
    const float* x    = (const float*)d_in[0];
    const float* k    = (const float*)d_in[1];
    const float* bias = (const float*)d_in[2];
    float* out        = (float*)d_out;

    dim3 block(256, 1, 1);
    dim3 grid(NWG, 1, 1);   // 3072 blocks, 1D, swizzled in-kernel
    corr2d_kernel<<<grid, block, 0, stream>>>(x, k, bias, out);
}

// Round 10
// 51.171 us; speedup vs baseline: 1.3533x; 1.0107x over previous
//
#include <hip/hip_runtime.h>

// 3x3 valid cross-correlation + bias, fp32.
// x: 6144x6144, k: 3x3, bias scalar -> out: 6142x6142.
// FINAL (revert to R5, the measured best at 51.1us):
// - 8 rows x 4 cols per thread, 10 input rows loaded flat upfront
//   (compiler rolls to VGPR=32 -> 69% occupancy; TLP > per-wave MLP,
//   proven by R6/R7 failures: forcing deep MLP cost occupancy and lost).
// - float4+float2 input loads, nontemporal float2 output stores
//   (8B-aligned: row stride 6142 and c0 both even), 32-bit indexing.
// - Chunked bijective XCD swizzle: y-adjacent bands of one column strip
//   on one XCD -> halo rows L2-hit (FETCH 85.6 -> 76.4 MB).
// Measured: 51.1us, logical traffic 341 MB -> 6.7 TB/s effective delivery
// = fabric ceiling. R8 (fewer logical bytes) and R6/R7 (more MLP) both null.

#define W_IN  6144
#define H_IN  6144
#define OW    6142
#define OH    6142
#define ROWS  8
#define GRID_X 6      // column-strip blocks (6*256 threads * 4 cols = 6144 >= 6142)
#define GRID_Y 768    // row bands of 8
#define NWG   (GRID_X * GRID_Y)   // 4608 = 8 XCDs * 576
#define WG_PER_XCD (NWG / 8)      // 576

typedef float f32x2 __attribute__((ext_vector_type(2)));
typedef float f32x4 __attribute__((ext_vector_type(4)));

template <bool INTERIOR>
__device__ __forceinline__ void body_main(const float* __restrict__ x,
                                          float* __restrict__ out,
                                          int c0, int r0,
                                          float k00, float k01, float k02,
                                          float k10, float k11, float k12,
                                          float k20, float k21, float k22,
                                          float bv)
{
    float v[ROWS + 2][6];
#pragma unroll
    for (int r = 0; r < ROWS + 2; ++r) {
        const int rr = r0 + r;
        if (INTERIOR || rr < H_IN) {
            const float* p = x + rr * W_IN + c0;
            const f32x4 a = *reinterpret_cast<const f32x4*>(p);
            const f32x2 c = *reinterpret_cast<const f32x2*>(p + 4);
            v[r][0] = a.x; v[r][1] = a.y; v[r][2] = a.z; v[r][3] = a.w;
            v[r][4] = c.x; v[r][5] = c.y;
        } else {
#pragma unroll
            for (int j = 0; j < 6; ++j) v[r][j] = 0.f;
        }
    }

#pragma unroll
    for (int m = 0; m < ROWS; ++m) {
        const int rr = r0 + m;
        if (INTERIOR || rr < OH) {
            float acc[4];
#pragma unroll
            for (int j = 0; j < 4; ++j) {
                acc[j] = bv
                    + v[m + 0][j] * k00 + v[m + 0][j + 1] * k01 + v[m + 0][j + 2] * k02
                    + v[m + 1][j] * k10 + v[m + 1][j + 1] * k11 + v[m + 1][j + 2] * k12
                    + v[m + 2][j] * k20 + v[m + 2][j + 1] * k21 + v[m + 2][j + 2] * k22;
            }
            float* po = out + rr * OW + c0;
            f32x2 s0; s0.x = acc[0]; s0.y = acc[1];
            f32x2 s1; s1.x = acc[2]; s1.y = acc[3];
            __builtin_nontemporal_store(s0, reinterpret_cast<f32x2*>(po));
            __builtin_nontemporal_store(s1, reinterpret_cast<f32x2*>(po + 2));
        }
    }
}

template <bool INTERIOR>
__device__ __forceinline__ void body_tail(const float* __restrict__ x,
                                          float* __restrict__ out,
                                          int c0, int r0,
                                          float k00, float k01, float k02,
                                          float k10, float k11, float k12,
                                          float k20, float k21, float k22,
                                          float bv)
{
    // c0 == 6140: output cols 6140..6141, input cols 6140..6143 (one float4).
    float v[ROWS + 2][4];
#pragma unroll
    for (int r = 0; r < ROWS + 2; ++r) {
        const int rr = r0 + r;
        if (INTERIOR || rr < H_IN) {
            const f32x4 a = *reinterpret_cast<const f32x4*>(x + rr * W_IN + c0);
            v[r][0] = a.x; v[r][1] = a.y; v[r][2] = a.z; v[r][3] = a.w;
        } else {
#pragma unroll
            for (int j = 0; j < 4; ++j) v[r][j] = 0.f;
        }
    }

#pragma unroll
    for (int m = 0; m < ROWS; ++m) {
        const int rr = r0 + m;
        if (INTERIOR || rr < OH) {
            float a0 = bv
                + v[m + 0][0] * k00 + v[m + 0][1] * k01 + v[m + 0][2] * k02
                + v[m + 1][0] * k10 + v[m + 1][1] * k11 + v[m + 1][2] * k12
                + v[m + 2][0] * k20 + v[m + 2][1] * k21 + v[m + 2][2] * k22;
            float a1 = bv
                + v[m + 0][1] * k00 + v[m + 0][2] * k01 + v[m + 0][3] * k02
                + v[m + 1][1] * k10 + v[m + 1][2] * k11 + v[m + 1][3] * k12
                + v[m + 2][1] * k20 + v[m + 2][2] * k21 + v[m + 2][3] * k22;
            f32x2 s0; s0.x = a0; s0.y = a1;
            __builtin_nontemporal_store(s0, reinterpret_cast<f32x2*>(out + rr * OW + c0));
        }
    }
}

__global__ __launch_bounds__(256)
void corr2d_kernel(const float* __restrict__ x,
                   const float* __restrict__ kk,
                   const float* __restrict__ bias,
                   float* __restrict__ out) {
    // Chunked bijective XCD swizzle: consecutive wg on one XCD are
    // y-adjacent bands of the same column strip -> halo rows L2-hit.
    const int id = blockIdx.x;                        // 0..4607
    const int wg = (id & 7) * WG_PER_XCD + (id >> 3); // bijection (4608 % 8 == 0)
    const int bx = wg / GRID_Y;                       // 0..5   column strip
    const int by = wg - bx * GRID_Y;                  // 0..767 row band

    const int t  = bx * 256 + (int)threadIdx.x;       // 0..1535
    const int c0 = t << 2;                            // 0,4,...,6140
    const int r0 = by * ROWS;

    const float k00 = kk[0], k01 = kk[1], k02 = kk[2];
    const float k10 = kk[3], k11 = kk[4], k12 = kk[5];
    const float k20 = kk[6], k21 = kk[7], k22 = kk[8];
    const float bv = bias[0];

    const bool interior = (r0 + ROWS + 1) < H_IN;     // input rows r0..r0+ROWS+1 all valid

    if (c0 + 4 <= OW) {
        if (interior) body_main<true >(x, out, c0, r0, k00, k01, k02, k10, k11, k12, k20, k21, k22, bv);
        else          body_main<false>(x, out, c0, r0, k00, k01, k02, k10, k11, k12, k20, k21, k22, bv);
    } else {
        if (interior) body_tail<true >(x, out, c0, r0, k00, k01, k02, k10, k11, k12, k20, k21, k22, bv);
        else          body_tail<false>(x, out, c0, r0, k00, k01, k02, k10, k11, k12, k20, k21, k22, bv);
    }
}

extern "C" void kernel_launch(void* const* d_in, const int* in_sizes, int n_in,
                              void* d_out, int out_size, void* d_ws, size_t ws_size,
                              hipStream_t stream) {
    const float* x    = (const float*)d_in[0];
    const float* k    = (const float*)d_in[1];
    const float* bias = (const float*)d_in[2];
    float* out        = (float*)d_out;

    dim3 block(256, 1, 1);
    dim3 grid(NWG, 1, 1);   // 4608 blocks, 1D, swizzled in-kernel
    corr2d_kernel<<<grid, block, 0, stream>>>(x, k, bias, out);
}